// Round 10
// baseline (484.945 us; speedup 1.0000x reference)
//
#include <hip/hip_runtime.h>
#include <hip/hip_bf16.h>
#include <cstdint>
#include <cstddef>

#define NN 64
#define CC 192
#define VV 25
#define TTT 300
#define TC 4            // t per block, 1 per wave
#define NTC 75          // 300/4, exact
#define GRID (NN*NTC)   // 4800

// workspace (u16 element offsets)
#define MFRAG_OFF 40960 // M fragment-major: 72 frags x 64 lanes x 8 bf16
#define WML_OFF 77824   // wm linear bf16[192]

// LDS: transpose tile [107 rows][88B] (pad->9472) + 4 x 3KB wave scratch
#define ROWT 88
#define TILE_BYTES 9472
#define LDS_TOTAL (TILE_BYTES + 4*3072)   // 21,760

typedef unsigned short u16;
typedef unsigned long long u64;
typedef short bf16x8 __attribute__((ext_vector_type(8)));
typedef float f32x4 __attribute__((ext_vector_type(4)));
typedef float f4 __attribute__((ext_vector_type(4)));

__device__ __forceinline__ u16 f2bf(float x) {
  union { float f; uint32_t u; } v; v.f = x;
  uint32_t r = v.u + 0x7fffu + ((v.u >> 16) & 1u);
  return (u16)(r >> 16);
}
__device__ __forceinline__ u64 pack4(f32x4 a) {
  return (u64)f2bf(a[0]) | ((u64)f2bf(a[1]) << 16) |
         ((u64)f2bf(a[2]) << 32) | ((u64)f2bf(a[3]) << 48);
}
// packed bf16 pair convert (compiler lowers to packed cvt on gfx950)
__device__ __forceinline__ uint32_t pk2(float a, float b) {
  __hip_bfloat162 h = __float22bfloat162_rn(float2{a, b});
  uint32_t u; __builtin_memcpy(&u, &h, 4); return u;
}

// prep: blocks 0..191 -> M fragment-major; block 192 -> wm linear bf16.
__global__ __launch_bounds__(192) void prep(const float* __restrict__ w1,
                                            const float* __restrict__ w2,
                                            const float* __restrict__ wm,
                                            u16* __restrict__ mb) {
  int c2 = threadIdx.x, b = blockIdx.x;
  if (b < CC) {
    float s = 0.f;
    for (int d = 0; d < CC; ++d) s += w1[d * CC + b] * w2[d * CC + c2];
    u16 h = f2bf(s);
    int cc = b >> 5, half = (b >> 4) & 1, lr = b & 15;
    int ks = c2 >> 5, l8 = (c2 & 31) >> 3, e = c2 & 7;
    int lane = l8 * 16 + lr;
    mb[MFRAG_OFF + (((cc * 2 + half) * 6 + ks) * 64 + lane) * 8 + e] = h;
  } else {
    mb[WML_OFF + c2] = f2bf(wm[c2]);
  }
}

// fused: block = (n, 4 t), 256 threads, wave = 1 t. 6 c-tile rounds of
// {c-pair dense reads -> packed-cvt -> 88B-row LDS tile -> barrier ->
//  b128 fragment harvest -> barrier}, then barrier-free register compute
// (pass1 Y=M@X via 3KB Y-bounce, pass2 sim += X^T Y, mask-MFMA,
//  stats centering, softmax, coalesced store).
__global__ __launch_bounds__(256, 6) void fused(const float* __restrict__ x1,
                                                const u16* __restrict__ mb,
                                                float* __restrict__ out) {
  __shared__ char lds[LDS_TOTAL];
  const int tid = threadIdx.x;
  const int wid = tid >> 6, lane = tid & 63, lr = lane & 15, lq = lane >> 4;
  char* YS = lds + TILE_BYTES + wid * 3072;  // Y-bounce / epilogue SIM [27][28] f32

  // XCD-chunked bijective swizzle (GRID % 8 == 0): adjacent t-chunks same XCD.
  int b = blockIdx.x;
  int logical = (b & 7) * (GRID / 8) + (b >> 3);
  int n = logical / NTC;
  int ch = logical - n * NTC;
  int t0 = ch * TC;
  int t = t0 + wid;

  const float* xb = x1 + (size_t)n * (CC * VV * TTT) + t0;

  // ---- 6 c-tile rounds: stage (c-pairs, packed cvt, b32 writes) + harvest ----
  bf16x8 sf[2][6];
  #pragma unroll
  for (int ct = 0; ct < 6; ++ct) {
    for (int job = tid; job < 400; job += 256) {
      int v = job % 25;
      int pr = job / 25;                       // c-pair 0..15
      const float* p = xb + (size_t)(ct * 32 + pr * 2) * (VV * TTT) + v * TTT;
      f4 a0 = *(const f4*)(p);
      f4 a1 = *(const f4*)(p + VV * TTT);
      #pragma unroll
      for (int dt = 0; dt < 4; ++dt) {
        int col = dt * 25 + v;
        *(uint32_t*)(lds + col * ROWT + pr * 4) = pk2(a0[dt], a1[dt]);
      }
    }
    __syncthreads();
    #pragma unroll
    for (int j = 0; j < 2; ++j)
      sf[j][ct] = *(const bf16x8*)(lds + (wid * VV + j * 16 + lr) * ROWT + lq * 16);
    __syncthreads();
  }

  // ---- register compute (no barriers) ----
  f32x4 pacc[2][2], macc[2];
  #pragma unroll
  for (int i = 0; i < 2; ++i) {
    macc[i] = (f32x4){0.f, 0.f, 0.f, 0.f};
    #pragma unroll
    for (int jx = 0; jx < 2; ++jx) pacc[i][jx] = (f32x4){0.f, 0.f, 0.f, 0.f};
  }

  const u16* mf = mb + MFRAG_OFF;
  #pragma unroll
  for (int cc = 0; cc < 6; ++cc) {
    // pass1: Y[c1-chunk 32][32 cols]; ks-outer so af loads once, 4 y-accs live
    f32x4 y00 = (f32x4){0.f,0.f,0.f,0.f}, y01 = y00, y10 = y00, y11 = y00;
    #pragma unroll
    for (int ks = 0; ks < 6; ++ks) {
      bf16x8 a0 = *(const bf16x8*)(mf + ((cc * 12 + ks) * 64 + lane) * 8);
      bf16x8 a1 = *(const bf16x8*)(mf + ((cc * 12 + 6 + ks) * 64 + lane) * 8);
      y00 = __builtin_amdgcn_mfma_f32_16x16x32_bf16(a0, sf[0][ks], y00, 0, 0, 0);
      y01 = __builtin_amdgcn_mfma_f32_16x16x32_bf16(a1, sf[0][ks], y01, 0, 0, 0);
      y10 = __builtin_amdgcn_mfma_f32_16x16x32_bf16(a0, sf[1][ks], y10, 0, 0, 0);
      y11 = __builtin_amdgcn_mfma_f32_16x16x32_bf16(a1, sf[1][ks], y11, 0, 0, 0);
    }
    *(u64*)(YS + (lr) * 80 + lq * 8) = pack4(y00);
    *(u64*)(YS + (lr) * 80 + 32 + lq * 8) = pack4(y01);
    *(u64*)(YS + (16 + lr) * 80 + lq * 8) = pack4(y10);
    *(u64*)(YS + (16 + lr) * 80 + 32 + lq * 8) = pack4(y11);

    // pass2 + mask (same-wave ordering)
    bf16x8 wmf = *(const bf16x8*)(mb + WML_OFF + cc * 32 + lq * 8);
    #pragma unroll
    for (int vt = 0; vt < 2; ++vt) {
      bf16x8 A = sf[vt][cc];
      macc[vt] = __builtin_amdgcn_mfma_f32_16x16x32_bf16(A, wmf, macc[vt], 0, 0, 0);
      #pragma unroll
      for (int wt = 0; wt < 2; ++wt) {
        bf16x8 B = *(const bf16x8*)(YS + (wt * 16 + lr) * 80 + lq * 16);
        pacc[vt][wt] = __builtin_amdgcn_mfma_f32_16x16x32_bf16(A, B, pacc[vt][wt], 0, 0, 0);
      }
    }
  }

  // ---- wave-private epilogue (Y-bounce dead; reuse as SIM [27][28] f32) ----
  float* SIMW = (float*)YS;
  #pragma unroll
  for (int vt = 0; vt < 2; ++vt)
    #pragma unroll
    for (int wt = 0; wt < 2; ++wt) {
      int w = wt * 16 + lr;
      if (w < VV) {
        #pragma unroll
        for (int i = 0; i < 4; ++i) {
          int v = vt * 16 + lq * 4 + i;
          if (v < VV) SIMW[v * 28 + w] = pacc[vt][wt][i];
        }
      }
    }
  if (lr == 0) {  // mask row 26 (macc identical across lr)
    #pragma unroll
    for (int j = 0; j < 2; ++j)
      #pragma unroll
      for (int i = 0; i < 4; ++i) {
        int v = j * 16 + lq * 4 + i;
        if (v < VV) SIMW[26 * 28 + v] = macc[j][i];
      }
  }

  float rs = 0.f, cs = 0.f;
  if (lane < VV) {
    #pragma unroll
    for (int w = 0; w < VV; ++w) rs += SIMW[lane * 28 + w];
    #pragma unroll
    for (int v = 0; v < VV; ++v) cs += SIMW[v * 28 + lane];
    SIMW[25 * 28 + lane] = cs;
  }
  float x = (lane < VV) ? cs : 0.f;
  #pragma unroll
  for (int s = 1; s < 64; s <<= 1) x += __shfl_xor(x, s);
  const float tot = x;

  if (lane < VV) {
    const int v = lane;
    const float base = -rs * 0.04f + tot * 0.0016f;
    const float isc = 0.07216878364870323f;  // 1/sqrt(192)
    float l[VV];
    float mx = -1e30f;
    #pragma unroll
    for (int w = 0; w < VV; ++w) {
      float val = (SIMW[v * 28 + w] - SIMW[25 * 28 + w] * 0.04f + base) * isc +
                  SIMW[26 * 28 + w];
      l[w] = val;
      mx = fmaxf(mx, val);
    }
    float sum = 0.f;
    #pragma unroll
    for (int w = 0; w < VV; ++w) { float e = __expf(l[w] - mx); l[w] = e; sum += e; }
    float rsc = 1.0f / sum;
    #pragma unroll
    for (int w = 0; w < VV; ++w) SIMW[v * 28 + w] = l[w] * rsc;
  }

  float* ob = out + (size_t)(n * TTT + t) * 625;
  for (int idx = lane; idx < 625; idx += 64) {
    int v = idx / VV, w = idx - v * VV;
    ob[idx] = SIMW[v * 28 + w];
  }
}

extern "C" void kernel_launch(void* const* d_in, const int* in_sizes, int n_in,
                              void* d_out, int out_size, void* d_ws, size_t ws_size,
                              hipStream_t stream) {
  const float* x1 = (const float*)d_in[0];
  const float* w1 = (const float*)d_in[1];
  const float* w2 = (const float*)d_in[2];
  const float* wm = (const float*)d_in[3];
  float* out = (float*)d_out;
  u16* mb = (u16*)d_ws;  // ~156 KB used

  hipLaunchKernelGGL(prep, dim3(CC + 1), dim3(CC), 0, stream, w1, w2, wm, mb);
  hipLaunchKernelGGL(fused, dim3(GRID), dim3(256), 0, stream, x1, mb, out);
}

// Round 11
// 215.205 us; speedup vs baseline: 2.2534x; 2.2534x over previous
//
#include <hip/hip_runtime.h>
#include <hip/hip_bf16.h>
#include <cstdint>
#include <cstddef>

#define NN 64
#define CC 192
#define VV 25
#define TTT 300
#define TC 4            // t per block, 1 per wave
#define NTC 75          // 300/4, exact
#define GRID (NN*NTC)   // 4800

// workspace (u16 element offsets)
#define MFRAG_OFF 40960 // M fragment-major: 72 frags x 64 lanes x 8 bf16
#define WML_OFF 77824   // wm linear bf16[192]

// LDS: transpose tile [107 rows][88B] (pad->9472) + 4 x 3KB wave scratch
#define ROWT 88
#define TILE_BYTES 9472
#define LDS_TOTAL (TILE_BYTES + 4*3072)   // 21,760

typedef unsigned short u16;
typedef unsigned long long u64;
typedef short bf16x8 __attribute__((ext_vector_type(8)));
typedef float f32x4 __attribute__((ext_vector_type(4)));
typedef float f4 __attribute__((ext_vector_type(4)));

__device__ __forceinline__ u16 f2bf(float x) {
  union { float f; uint32_t u; } v; v.f = x;
  uint32_t r = v.u + 0x7fffu + ((v.u >> 16) & 1u);
  return (u16)(r >> 16);
}
__device__ __forceinline__ u64 pack4(f32x4 a) {
  return (u64)f2bf(a[0]) | ((u64)f2bf(a[1]) << 16) |
         ((u64)f2bf(a[2]) << 32) | ((u64)f2bf(a[3]) << 48);
}
// packed bf16 pair convert (compiler lowers to packed cvt on gfx950)
__device__ __forceinline__ uint32_t pk2(float a, float b) {
  __hip_bfloat162 h = __float22bfloat162_rn(float2{a, b});
  uint32_t u; __builtin_memcpy(&u, &h, 4); return u;
}

// prep: blocks 0..191 -> M fragment-major; block 192 -> wm linear bf16.
__global__ __launch_bounds__(192) void prep(const float* __restrict__ w1,
                                            const float* __restrict__ w2,
                                            const float* __restrict__ wm,
                                            u16* __restrict__ mb) {
  int c2 = threadIdx.x, b = blockIdx.x;
  if (b < CC) {
    float s = 0.f;
    for (int d = 0; d < CC; ++d) s += w1[d * CC + b] * w2[d * CC + c2];
    u16 h = f2bf(s);
    int cc = b >> 5, half = (b >> 4) & 1, lr = b & 15;
    int ks = c2 >> 5, l8 = (c2 & 31) >> 3, e = c2 & 7;
    int lane = l8 * 16 + lr;
    mb[MFRAG_OFF + (((cc * 2 + half) * 6 + ks) * 64 + lane) * 8 + e] = h;
  } else {
    mb[WML_OFF + c2] = f2bf(wm[c2]);
  }
}

// fused: block = (n, 4 t), 256 threads, wave = 1 t. 6 c-tile rounds of
// {c-pair dense reads -> packed-cvt -> 88B-row LDS tile -> barrier ->
//  b128 fragment harvest -> barrier}, then barrier-free register compute
// (pass1 Y=M@X via 3KB Y-bounce, pass2 sim += X^T Y, mask-MFMA,
//  stats centering, softmax, coalesced store).
// launch_bounds(256,4): 128 VGPR cap -> NO spills (R10's (256,6) forced ~85
// VGPRs and generated 1.4GB of scratch traffic).
__global__ __launch_bounds__(256, 4) void fused(const float* __restrict__ x1,
                                                const u16* __restrict__ mb,
                                                float* __restrict__ out) {
  __shared__ char lds[LDS_TOTAL];
  const int tid = threadIdx.x;
  const int wid = tid >> 6, lane = tid & 63, lr = lane & 15, lq = lane >> 4;
  char* YS = lds + TILE_BYTES + wid * 3072;  // Y-bounce / epilogue SIM [27][28] f32

  // XCD-chunked bijective swizzle (GRID % 8 == 0): adjacent t-chunks same XCD.
  int b = blockIdx.x;
  int logical = (b & 7) * (GRID / 8) + (b >> 3);
  int n = logical / NTC;
  int ch = logical - n * NTC;
  int t0 = ch * TC;
  int t = t0 + wid;

  const float* xb = x1 + (size_t)n * (CC * VV * TTT) + t0;

  // ---- 6 c-tile rounds: stage (c-pairs, packed cvt, b32 writes) + harvest ----
  bf16x8 sf[2][6];
  #pragma unroll
  for (int ct = 0; ct < 6; ++ct) {
    for (int job = tid; job < 400; job += 256) {
      int v = job % 25;
      int pr = job / 25;                       // c-pair 0..15
      const float* p = xb + (size_t)(ct * 32 + pr * 2) * (VV * TTT) + v * TTT;
      f4 a0 = *(const f4*)(p);
      f4 a1 = *(const f4*)(p + VV * TTT);
      #pragma unroll
      for (int dt = 0; dt < 4; ++dt) {
        int col = dt * 25 + v;
        *(uint32_t*)(lds + col * ROWT + pr * 4) = pk2(a0[dt], a1[dt]);
      }
    }
    __syncthreads();
    #pragma unroll
    for (int j = 0; j < 2; ++j)
      sf[j][ct] = *(const bf16x8*)(lds + (wid * VV + j * 16 + lr) * ROWT + lq * 16);
    __syncthreads();
  }

  // ---- register compute (no barriers) ----
  f32x4 pacc[2][2], macc[2];
  #pragma unroll
  for (int i = 0; i < 2; ++i) {
    macc[i] = (f32x4){0.f, 0.f, 0.f, 0.f};
    #pragma unroll
    for (int jx = 0; jx < 2; ++jx) pacc[i][jx] = (f32x4){0.f, 0.f, 0.f, 0.f};
  }

  const u16* mf = mb + MFRAG_OFF;
  #pragma unroll
  for (int cc = 0; cc < 6; ++cc) {
    // pass1: Y[c1-chunk 32][32 cols]; ks-outer so af loads once, 4 y-accs live
    f32x4 y00 = (f32x4){0.f,0.f,0.f,0.f}, y01 = y00, y10 = y00, y11 = y00;
    #pragma unroll
    for (int ks = 0; ks < 6; ++ks) {
      bf16x8 a0 = *(const bf16x8*)(mf + ((cc * 12 + ks) * 64 + lane) * 8);
      bf16x8 a1 = *(const bf16x8*)(mf + ((cc * 12 + 6 + ks) * 64 + lane) * 8);
      y00 = __builtin_amdgcn_mfma_f32_16x16x32_bf16(a0, sf[0][ks], y00, 0, 0, 0);
      y01 = __builtin_amdgcn_mfma_f32_16x16x32_bf16(a1, sf[0][ks], y01, 0, 0, 0);
      y10 = __builtin_amdgcn_mfma_f32_16x16x32_bf16(a0, sf[1][ks], y10, 0, 0, 0);
      y11 = __builtin_amdgcn_mfma_f32_16x16x32_bf16(a1, sf[1][ks], y11, 0, 0, 0);
    }
    *(u64*)(YS + (lr) * 80 + lq * 8) = pack4(y00);
    *(u64*)(YS + (lr) * 80 + 32 + lq * 8) = pack4(y01);
    *(u64*)(YS + (16 + lr) * 80 + lq * 8) = pack4(y10);
    *(u64*)(YS + (16 + lr) * 80 + 32 + lq * 8) = pack4(y11);

    // pass2 + mask (same-wave ordering)
    bf16x8 wmf = *(const bf16x8*)(mb + WML_OFF + cc * 32 + lq * 8);
    #pragma unroll
    for (int vt = 0; vt < 2; ++vt) {
      bf16x8 A = sf[vt][cc];
      macc[vt] = __builtin_amdgcn_mfma_f32_16x16x32_bf16(A, wmf, macc[vt], 0, 0, 0);
      #pragma unroll
      for (int wt = 0; wt < 2; ++wt) {
        bf16x8 B = *(const bf16x8*)(YS + (wt * 16 + lr) * 80 + lq * 16);
        pacc[vt][wt] = __builtin_amdgcn_mfma_f32_16x16x32_bf16(A, B, pacc[vt][wt], 0, 0, 0);
      }
    }
  }

  // ---- wave-private epilogue (Y-bounce dead; reuse as SIM [27][28] f32) ----
  float* SIMW = (float*)YS;
  #pragma unroll
  for (int vt = 0; vt < 2; ++vt)
    #pragma unroll
    for (int wt = 0; wt < 2; ++wt) {
      int w = wt * 16 + lr;
      if (w < VV) {
        #pragma unroll
        for (int i = 0; i < 4; ++i) {
          int v = vt * 16 + lq * 4 + i;
          if (v < VV) SIMW[v * 28 + w] = pacc[vt][wt][i];
        }
      }
    }
  if (lr == 0) {  // mask row 26 (macc identical across lr)
    #pragma unroll
    for (int j = 0; j < 2; ++j)
      #pragma unroll
      for (int i = 0; i < 4; ++i) {
        int v = j * 16 + lq * 4 + i;
        if (v < VV) SIMW[26 * 28 + v] = macc[j][i];
      }
  }

  float rs = 0.f, cs = 0.f;
  if (lane < VV) {
    #pragma unroll
    for (int w = 0; w < VV; ++w) rs += SIMW[lane * 28 + w];
    #pragma unroll
    for (int v = 0; v < VV; ++v) cs += SIMW[v * 28 + lane];
    SIMW[25 * 28 + lane] = cs;
  }
  float x = (lane < VV) ? cs : 0.f;
  #pragma unroll
  for (int s = 1; s < 64; s <<= 1) x += __shfl_xor(x, s);
  const float tot = x;

  if (lane < VV) {
    const int v = lane;
    const float base = -rs * 0.04f + tot * 0.0016f;
    const float isc = 0.07216878364870323f;  // 1/sqrt(192)
    float l[VV];
    float mx = -1e30f;
    #pragma unroll
    for (int w = 0; w < VV; ++w) {
      float val = (SIMW[v * 28 + w] - SIMW[25 * 28 + w] * 0.04f + base) * isc +
                  SIMW[26 * 28 + w];
      l[w] = val;
      mx = fmaxf(mx, val);
    }
    float sum = 0.f;
    #pragma unroll
    for (int w = 0; w < VV; ++w) { float e = __expf(l[w] - mx); l[w] = e; sum += e; }
    float rsc = 1.0f / sum;
    #pragma unroll
    for (int w = 0; w < VV; ++w) SIMW[v * 28 + w] = l[w] * rsc;
  }

  float* ob = out + (size_t)(n * TTT + t) * 625;
  for (int idx = lane; idx < 625; idx += 64) {
    int v = idx / VV, w = idx - v * VV;
    ob[idx] = SIMW[v * 28 + w];
  }
}

extern "C" void kernel_launch(void* const* d_in, const int* in_sizes, int n_in,
                              void* d_out, int out_size, void* d_ws, size_t ws_size,
                              hipStream_t stream) {
  const float* x1 = (const float*)d_in[0];
  const float* w1 = (const float*)d_in[1];
  const float* w2 = (const float*)d_in[2];
  const float* wm = (const float*)d_in[3];
  float* out = (float*)d_out;
  u16* mb = (u16*)d_ws;  // ~156 KB used

  hipLaunchKernelGGL(prep, dim3(CC + 1), dim3(CC), 0, stream, w1, w2, wm, mb);
  hipLaunchKernelGGL(fused, dim3(GRID), dim3(256), 0, stream, x1, mb, out);
}

// Round 12
// 191.801 us; speedup vs baseline: 2.5284x; 1.1220x over previous
//
#include <hip/hip_runtime.h>
#include <hip/hip_bf16.h>
#include <cstdint>
#include <cstddef>

#define NN 64
#define CC 192
#define VV 25
#define TTT 300
#define TC 16           // t per block, 1 per wave (16 waves)
#define NTC 19          // ceil(300/16); last chunk has 12 real t
#define GRID (NN*NTC)   // 1216 (% 8 == 0)

// workspace (u16 element offsets)
#define MFRAG_OFF 40960 // M fragment-major: 72 frags x 64 lanes x 8 bf16
#define WML_OFF 77824   // wm linear bf16[192]

// LDS: transpose tile [400(+7 overread) rows][88B] = 35,816 B, OVERLAID with
// 16 x 3KB wave scratch (Y-bounce/SIM) used only after the final harvest barrier.
#define ROWT 88
#define LDS_TOTAL 49152

typedef unsigned short u16;
typedef unsigned long long u64;
typedef short bf16x8 __attribute__((ext_vector_type(8)));
typedef float f32x4 __attribute__((ext_vector_type(4)));
typedef float f4 __attribute__((ext_vector_type(4)));

__device__ __forceinline__ u16 f2bf(float x) {
  union { float f; uint32_t u; } v; v.f = x;
  uint32_t r = v.u + 0x7fffu + ((v.u >> 16) & 1u);
  return (u16)(r >> 16);
}
__device__ __forceinline__ u64 pack4(f32x4 a) {
  return (u64)f2bf(a[0]) | ((u64)f2bf(a[1]) << 16) |
         ((u64)f2bf(a[2]) << 32) | ((u64)f2bf(a[3]) << 48);
}
// packed bf16 pair convert (compiler lowers to packed cvt on gfx950)
__device__ __forceinline__ uint32_t pk2(float a, float b) {
  __hip_bfloat162 h = __float22bfloat162_rn(float2{a, b});
  uint32_t u; __builtin_memcpy(&u, &h, 4); return u;
}

// prep: blocks 0..191 -> M fragment-major; block 192 -> wm linear bf16.
__global__ __launch_bounds__(192) void prep(const float* __restrict__ w1,
                                            const float* __restrict__ w2,
                                            const float* __restrict__ wm,
                                            u16* __restrict__ mb) {
  int c2 = threadIdx.x, b = blockIdx.x;
  if (b < CC) {
    float s = 0.f;
    for (int d = 0; d < CC; ++d) s += w1[d * CC + b] * w2[d * CC + c2];
    u16 h = f2bf(s);
    int cc = b >> 5, half = (b >> 4) & 1, lr = b & 15;
    int ks = c2 >> 5, l8 = (c2 & 31) >> 3, e = c2 & 7;
    int lane = l8 * 16 + lr;
    mb[MFRAG_OFF + (((cc * 2 + half) * 6 + ks) * 64 + lane) * 8 + e] = h;
  } else {
    mb[WML_OFF + c2] = f2bf(wm[c2]);
  }
}

// fused: block = (n, 16 t), 1024 threads, wave = 1 t.
// Staging (6 c-tile rounds): 4 consecutive lanes read the 4x16B segments of ONE
// 64B x1 line (full-line coalescing; every line fetched exactly once on-chip);
// shfl_xor(4) pairs (c,c+1); even-c lanes write packed bf16 b32 into the
// [tt*25+v][c] tile (bank-conflict-free). Harvest b128 fragments into sf regs.
// Then R11's register compute: pass1 Y=M@X (Y-bounce in wave scratch), pass2
// sim += X^T Y, mask-MFMA, stats centering, softmax, coalesced store.
__global__ __launch_bounds__(1024, 4) void fused(const float* __restrict__ x1,
                                                 const u16* __restrict__ mb,
                                                 float* __restrict__ out) {
  __shared__ char lds[LDS_TOTAL];
  const int tid = threadIdx.x;
  const int wid = tid >> 6, lane = tid & 63, lr = lane & 15, lq = lane >> 4;
  char* YS = lds + wid * 3072;  // valid only after final harvest barrier

  // XCD-chunked bijective swizzle (GRID % 8 == 0)
  int b = blockIdx.x;
  int logical = (b & 7) * (GRID / 8) + (b >> 3);
  int n = logical / NTC;
  int ch = logical - n * NTC;
  int t0 = ch * TC;
  int t = t0 + wid;
  const bool lastch = (t0 + TC > TTT);

  const float* xb = x1 + (size_t)n * (CC * VV * TTT) + t0;

  // ---- 6 c-tile rounds: coalesced stage + fragment harvest ----
  bf16x8 sf[2][6];
  #pragma unroll
  for (int ct = 0; ct < 6; ++ct) {
    #pragma unroll
    for (int it = 0; it < 4; ++it) {
      int job = it * 1024 + tid;            // job = (row r, seg): r = v*32+cl
      if (job < 3200) {
        int r = job >> 2, seg = job & 3;
        int v = r >> 5, cl = r & 31;
        int sege = (lastch && seg == 3) ? 2 : seg;  // clamp: stay in-bounds
        f4 a = *(const f4*)(xb + (size_t)(ct * 32 + cl) * (VV * TTT) + v * TTT + sege * 4);
        float p0 = __shfl_xor(a[0], 4);     // partner lane holds (c^1, v), same seg
        float p1 = __shfl_xor(a[1], 4);
        float p2 = __shfl_xor(a[2], 4);
        float p3 = __shfl_xor(a[3], 4);
        if (!(cl & 1)) {
          int colb = (cl >> 1) * 4;
          char* base = lds + (size_t)(seg * 4 * 25 + v) * ROWT + colb;
          *(uint32_t*)(base)                 = pk2(a[0], p0);
          *(uint32_t*)(base + 25 * ROWT)     = pk2(a[1], p1);
          *(uint32_t*)(base + 50 * ROWT)     = pk2(a[2], p2);
          *(uint32_t*)(base + 75 * ROWT)     = pk2(a[3], p3);
        }
      }
    }
    __syncthreads();
    #pragma unroll
    for (int j = 0; j < 2; ++j)
      sf[j][ct] = *(const bf16x8*)(lds + (wid * VV + j * 16 + lr) * ROWT + lq * 16);
    __syncthreads();  // tile reusable (next round / scratch overlay)
  }

  // ---- register compute (no barriers) ----
  f32x4 pacc[2][2], macc[2];
  #pragma unroll
  for (int i = 0; i < 2; ++i) {
    macc[i] = (f32x4){0.f, 0.f, 0.f, 0.f};
    #pragma unroll
    for (int jx = 0; jx < 2; ++jx) pacc[i][jx] = (f32x4){0.f, 0.f, 0.f, 0.f};
  }

  const u16* mf = mb + MFRAG_OFF;
  #pragma unroll
  for (int cc = 0; cc < 6; ++cc) {
    // pass1: Y[c1-chunk 32][32 cols]; ks-outer so af loads once, 4 y-accs live
    f32x4 y00 = (f32x4){0.f,0.f,0.f,0.f}, y01 = y00, y10 = y00, y11 = y00;
    #pragma unroll
    for (int ks = 0; ks < 6; ++ks) {
      bf16x8 a0 = *(const bf16x8*)(mf + ((cc * 12 + ks) * 64 + lane) * 8);
      bf16x8 a1 = *(const bf16x8*)(mf + ((cc * 12 + 6 + ks) * 64 + lane) * 8);
      y00 = __builtin_amdgcn_mfma_f32_16x16x32_bf16(a0, sf[0][ks], y00, 0, 0, 0);
      y01 = __builtin_amdgcn_mfma_f32_16x16x32_bf16(a1, sf[0][ks], y01, 0, 0, 0);
      y10 = __builtin_amdgcn_mfma_f32_16x16x32_bf16(a0, sf[1][ks], y10, 0, 0, 0);
      y11 = __builtin_amdgcn_mfma_f32_16x16x32_bf16(a1, sf[1][ks], y11, 0, 0, 0);
    }
    *(u64*)(YS + (lr) * 80 + lq * 8) = pack4(y00);
    *(u64*)(YS + (lr) * 80 + 32 + lq * 8) = pack4(y01);
    *(u64*)(YS + (16 + lr) * 80 + lq * 8) = pack4(y10);
    *(u64*)(YS + (16 + lr) * 80 + 32 + lq * 8) = pack4(y11);

    // pass2 + mask (same-wave ordering)
    bf16x8 wmf = *(const bf16x8*)(mb + WML_OFF + cc * 32 + lq * 8);
    #pragma unroll
    for (int vt = 0; vt < 2; ++vt) {
      bf16x8 A = sf[vt][cc];
      macc[vt] = __builtin_amdgcn_mfma_f32_16x16x32_bf16(A, wmf, macc[vt], 0, 0, 0);
      #pragma unroll
      for (int wt = 0; wt < 2; ++wt) {
        bf16x8 B = *(const bf16x8*)(YS + (wt * 16 + lr) * 80 + lq * 16);
        pacc[vt][wt] = __builtin_amdgcn_mfma_f32_16x16x32_bf16(A, B, pacc[vt][wt], 0, 0, 0);
      }
    }
  }

  // ---- wave-private epilogue (Y-bounce dead; reuse as SIM [27][28] f32) ----
  float* SIMW = (float*)YS;
  #pragma unroll
  for (int vt = 0; vt < 2; ++vt)
    #pragma unroll
    for (int wt = 0; wt < 2; ++wt) {
      int w = wt * 16 + lr;
      if (w < VV) {
        #pragma unroll
        for (int i = 0; i < 4; ++i) {
          int v = vt * 16 + lq * 4 + i;
          if (v < VV) SIMW[v * 28 + w] = pacc[vt][wt][i];
        }
      }
    }
  if (lr == 0) {  // mask row 26 (macc identical across lr)
    #pragma unroll
    for (int j = 0; j < 2; ++j)
      #pragma unroll
      for (int i = 0; i < 4; ++i) {
        int v = j * 16 + lq * 4 + i;
        if (v < VV) SIMW[26 * 28 + v] = macc[j][i];
      }
  }

  float rs = 0.f, cs = 0.f;
  if (lane < VV) {
    #pragma unroll
    for (int w = 0; w < VV; ++w) rs += SIMW[lane * 28 + w];
    #pragma unroll
    for (int v = 0; v < VV; ++v) cs += SIMW[v * 28 + lane];
    SIMW[25 * 28 + lane] = cs;
  }
  float x = (lane < VV) ? cs : 0.f;
  #pragma unroll
  for (int s = 1; s < 64; s <<= 1) x += __shfl_xor(x, s);
  const float tot = x;

  if (lane < VV) {
    const int v = lane;
    const float base = -rs * 0.04f + tot * 0.0016f;
    const float isc = 0.07216878364870323f;  // 1/sqrt(192)
    float l[VV];
    float mx = -1e30f;
    #pragma unroll
    for (int w = 0; w < VV; ++w) {
      float val = (SIMW[v * 28 + w] - SIMW[25 * 28 + w] * 0.04f + base) * isc +
                  SIMW[26 * 28 + w];
      l[w] = val;
      mx = fmaxf(mx, val);
    }
    float sum = 0.f;
    #pragma unroll
    for (int w = 0; w < VV; ++w) { float e = __expf(l[w] - mx); l[w] = e; sum += e; }
    float rsc = 1.0f / sum;
    #pragma unroll
    for (int w = 0; w < VV; ++w) SIMW[v * 28 + w] = l[w] * rsc;
  }

  if (t < TTT) {
    float* ob = out + (size_t)(n * TTT + t) * 625;
    for (int idx = lane; idx < 625; idx += 64) {
      int v = idx / VV, w = idx - v * VV;
      ob[idx] = SIMW[v * 28 + w];
    }
  }
}

extern "C" void kernel_launch(void* const* d_in, const int* in_sizes, int n_in,
                              void* d_out, int out_size, void* d_ws, size_t ws_size,
                              hipStream_t stream) {
  const float* x1 = (const float*)d_in[0];
  const float* w1 = (const float*)d_in[1];
  const float* w2 = (const float*)d_in[2];
  const float* wm = (const float*)d_in[3];
  float* out = (float*)d_out;
  u16* mb = (u16*)d_ws;  // ~156 KB used

  hipLaunchKernelGGL(prep, dim3(CC + 1), dim3(CC), 0, stream, w1, w2, wm, mb);
  hipLaunchKernelGGL(fused, dim3(GRID), dim3(1024), 0, stream, x1, mb, out);
}